// Round 1
// baseline (687.757 us; speedup 1.0000x reference)
//
#include <hip/hip_runtime.h>
#include <hip/hip_bf16.h>

// Problem constants
#define B_   4
#define N_   4096
#define IND  512
#define ATT  64
#define QKD  128   // 2*ATT

// ---------------------------------------------------------------------------
// GEMM NT: C[M][Nout] = X[M][K] @ W[Nout][K]^T   (all f32, row-major)
// 64x64 tile, K-tile 32, 256 threads, 4x4 micro-tile per thread.
// LDS stored transposed (Xs[k][m]) so the inner loop is two ds_read_b128.
// ---------------------------------------------------------------------------
__global__ __launch_bounds__(256)
void gemm_nt_f32(const float* __restrict__ X, const float* __restrict__ W,
                 float* __restrict__ C, int M, int K, int Nout) {
  __shared__ __align__(16) float Xs[32][68];
  __shared__ __align__(16) float Ws[32][68];
  const int tid = threadIdx.x;
  const int tx = tid & 15, ty = tid >> 4;
  const int m0 = blockIdx.x * 64, n0 = blockIdx.y * 64;

  float acc[4][4] = {};

  for (int k0 = 0; k0 < K; k0 += 32) {
    // 64 rows x 32 cols for each of X,W: 512 float4 total, 2 per thread each.
    for (int f = tid; f < 512; f += 256) {
      const int r = f >> 3;              // 0..63
      const int c4 = (f & 7) << 2;       // 0,4,...,28
      const float4 vx = *(const float4*)(X + (size_t)(m0 + r) * K + k0 + c4);
      Xs[c4 + 0][r] = vx.x; Xs[c4 + 1][r] = vx.y;
      Xs[c4 + 2][r] = vx.z; Xs[c4 + 3][r] = vx.w;
      const float4 vw = *(const float4*)(W + (size_t)(n0 + r) * K + k0 + c4);
      Ws[c4 + 0][r] = vw.x; Ws[c4 + 1][r] = vw.y;
      Ws[c4 + 2][r] = vw.z; Ws[c4 + 3][r] = vw.w;
    }
    __syncthreads();

#pragma unroll
    for (int kk = 0; kk < 32; ++kk) {
      const float4 a = *(const float4*)&Xs[kk][ty << 2];
      const float4 b = *(const float4*)&Ws[kk][tx << 2];
      const float av[4] = {a.x, a.y, a.z, a.w};
      const float bv[4] = {b.x, b.y, b.z, b.w};
#pragma unroll
      for (int i = 0; i < 4; ++i)
#pragma unroll
        for (int j = 0; j < 4; ++j) acc[i][j] += av[i] * bv[j];
    }
    __syncthreads();
  }

#pragma unroll
  for (int i = 0; i < 4; ++i) {
    float4 o = make_float4(acc[i][0], acc[i][1], acc[i][2], acc[i][3]);
    *(float4*)(C + (size_t)(m0 + (ty << 2) + i) * Nout + n0 + (tx << 2)) = o;
  }
}

// ---------------------------------------------------------------------------
// Masked score: wpre[b,n] = (1/8) * q[b,n] . ( sum_{m: adj[b,n,m]!=0} k[b,m] )
// adj is exactly binary, so no multiplies: ballot the nonzeros, add k rows.
// One wave (64 lanes) per output row; lane e owns channel e of ka.
// ---------------------------------------------------------------------------
__global__ __launch_bounds__(256)
void masked_score(const float* __restrict__ adj, const float* __restrict__ qk,
                  float* __restrict__ wpre) {
  const int wid  = threadIdx.x >> 6;              // wave in block: 0..3
  const int lane = threadIdx.x & 63;
  const int row  = blockIdx.x * 4 + wid;          // 0 .. B*N-1
  const int b = row >> 12;                        // /4096
  const int n = row & (N_ - 1);

  const float* adjrow = adj + (size_t)row * N_;
  const float* kbase  = qk + (size_t)b * N_ * QKD + ATT;  // k part
  float ka = 0.f;

  for (int s = 0; s < N_ / 256; ++s) {            // 16 steps of 256 m's
    const float4 v = *(const float4*)(adjrow + (size_t)(s * 64 + lane) * 4);
    const float vv[4] = {v.x, v.y, v.z, v.w};
#pragma unroll
    for (int j = 0; j < 4; ++j) {
      unsigned long long mk = __ballot(vv[j] != 0.f);
      while (mk) {
        const int L = __builtin_ctzll(mk);
        mk &= (mk - 1);
        const int m = s * 256 + L * 4 + j;
        ka += kbase[(size_t)m * QKD + lane];      // coalesced 256B row read
      }
    }
  }

  const float q = qk[(size_t)b * N_ * QKD + (size_t)n * QKD + lane];
  float val = q * ka;
#pragma unroll
  for (int off = 32; off; off >>= 1) val += __shfl_xor(val, off);
  if (lane == 0) wpre[row] = val * 0.125f;        // 1/sqrt(64)
}

// ---------------------------------------------------------------------------
// Softmax over the bag dimension (N=4096) per batch, in-place on wpre.
// ---------------------------------------------------------------------------
__global__ __launch_bounds__(256)
void softmax_bag(float* __restrict__ w) {
  __shared__ float red[256];
  const int b = blockIdx.x;
  float* wb = w + (size_t)b * N_;
  const int t = threadIdx.x;

  float vals[16];
  float mx = -1e30f;
#pragma unroll
  for (int i = 0; i < 16; ++i) {
    vals[i] = wb[t + i * 256];
    mx = fmaxf(mx, vals[i]);
  }
  red[t] = mx; __syncthreads();
  for (int s = 128; s; s >>= 1) {
    if (t < s) red[t] = fmaxf(red[t], red[t + s]);
    __syncthreads();
  }
  mx = red[0];
  __syncthreads();

  float sum = 0.f;
#pragma unroll
  for (int i = 0; i < 16; ++i) {
    vals[i] = expf(vals[i] - mx);
    sum += vals[i];
  }
  red[t] = sum; __syncthreads();
  for (int s = 128; s; s >>= 1) {
    if (t < s) red[t] += red[t + s];
    __syncthreads();
  }
  const float inv = 1.f / red[0];
#pragma unroll
  for (int i = 0; i < 16; ++i) wb[t + i * 256] = vals[i] * inv;
}

// ---------------------------------------------------------------------------
// out[b,n,:] *= w[b,n]   (v was written directly into d_out)
// ---------------------------------------------------------------------------
__global__ __launch_bounds__(256)
void scale_v(float* __restrict__ out, const float* __restrict__ w, int total4) {
  int idx = blockIdx.x * blockDim.x + threadIdx.x;
  const int stride = gridDim.x * blockDim.x;
  for (; idx < total4; idx += stride) {
    float4 v = ((const float4*)out)[idx];
    const float s = w[idx >> 7];                  // 512/4 = 128 float4 per row
    v.x *= s; v.y *= s; v.z *= s; v.w *= s;
    ((float4*)out)[idx] = v;
  }
}

extern "C" void kernel_launch(void* const* d_in, const int* in_sizes, int n_in,
                              void* d_out, int out_size, void* d_ws, size_t ws_size,
                              hipStream_t stream) {
  const float* x    = (const float*)d_in[0];   // (B,N,512)
  const float* adj  = (const float*)d_in[1];   // (B,N,N)
  const float* W_qk = (const float*)d_in[2];   // (128,512)
  const float* W_v  = (const float*)d_in[3];   // (512,512)
  float* out = (float*)d_out;                  // (B,N,512)

  float* qk   = (float*)d_ws;                            // B*N*128 floats (8 MB)
  float* wpre = qk + (size_t)B_ * N_ * QKD;              // B*N floats

  const int M = B_ * N_;  // 16384

  // v = x @ W_v^T  -> directly into d_out
  {
    dim3 grid(M / 64, IND / 64);
    gemm_nt_f32<<<grid, 256, 0, stream>>>(x, W_v, out, M, IND, IND);
  }
  // qk = x @ W_qk^T -> workspace
  {
    dim3 grid(M / 64, QKD / 64);
    gemm_nt_f32<<<grid, 256, 0, stream>>>(x, W_qk, qk, M, IND, QKD);
  }
  // wpre[b,n] = q.(adj-selected sum of k) / 8
  masked_score<<<M / 4, 256, 0, stream>>>(adj, qk, wpre);
  // softmax over bag dim
  softmax_bag<<<B_, 256, 0, stream>>>(wpre);
  // out *= w
  const int total4 = M * (IND / 4);
  scale_v<<<2048, 256, 0, stream>>>(out, wpre, total4);
}

// Round 3
// 625.395 us; speedup vs baseline: 1.0997x; 1.0997x over previous
//
#include <hip/hip_runtime.h>
#include <hip/hip_bf16.h>

// Problem constants
#define B_   4
#define N_   4096
#define IND  512
#define ATT  64
#define QKD  128   // 2*ATT

// adj@k GEMM tiling
#define KSPLIT 4
#define KCHUNK 1024   // 4096 / KSPLIT
#define MT 128
#define KT 64

// ---------------------------------------------------------------------------
// GEMM NT: C[M][Nout] = X[M][K] @ W[Nout][K]^T   (all f32, row-major)
// 64x64 tile, K-tile 32, 256 threads, 4x4 micro-tile per thread.
// ---------------------------------------------------------------------------
__global__ __launch_bounds__(256)
void gemm_nt_f32(const float* __restrict__ X, const float* __restrict__ W,
                 float* __restrict__ C, int M, int K, int Nout) {
  __shared__ __align__(16) float Xs[32][68];
  __shared__ __align__(16) float Ws[32][68];
  const int tid = threadIdx.x;
  const int tx = tid & 15, ty = tid >> 4;
  const int m0 = blockIdx.x * 64, n0 = blockIdx.y * 64;

  float acc[4][4] = {};

  for (int k0 = 0; k0 < K; k0 += 32) {
    for (int f = tid; f < 512; f += 256) {
      const int r = f >> 3;              // 0..63
      const int c4 = (f & 7) << 2;       // 0,4,...,28
      const float4 vx = *(const float4*)(X + (size_t)(m0 + r) * K + k0 + c4);
      Xs[c4 + 0][r] = vx.x; Xs[c4 + 1][r] = vx.y;
      Xs[c4 + 2][r] = vx.z; Xs[c4 + 3][r] = vx.w;
      const float4 vw = *(const float4*)(W + (size_t)(n0 + r) * K + k0 + c4);
      Ws[c4 + 0][r] = vw.x; Ws[c4 + 1][r] = vw.y;
      Ws[c4 + 2][r] = vw.z; Ws[c4 + 3][r] = vw.w;
    }
    __syncthreads();

#pragma unroll
    for (int kk = 0; kk < 32; ++kk) {
      const float4 a = *(const float4*)&Xs[kk][ty << 2];
      const float4 b = *(const float4*)&Ws[kk][tx << 2];
      const float av[4] = {a.x, a.y, a.z, a.w};
      const float bv[4] = {b.x, b.y, b.z, b.w};
#pragma unroll
      for (int i = 0; i < 4; ++i)
#pragma unroll
        for (int j = 0; j < 4; ++j) acc[i][j] += av[i] * bv[j];
    }
    __syncthreads();
  }

#pragma unroll
  for (int i = 0; i < 4; ++i) {
    float4 o = make_float4(acc[i][0], acc[i][1], acc[i][2], acc[i][3]);
    *(float4*)(C + (size_t)(m0 + (ty << 2) + i) * Nout + n0 + (tx << 2)) = o;
  }
}

// ---------------------------------------------------------------------------
// ka_partial = adj @ k  (dense f32, split-K, deterministic partials)
// A = adj (b, 4096, 4096) row-major; B = k read strided from qk workspace
// (row m of k = qk[b, m, 64:128], contiguous 64 floats at stride 128).
// Block: 256 threads, tile 128(M) x 64(N=ATT), K-tile 64 in LDS.
// Micro-tile 8x4 per thread: 32 FMA per 3 ds_read_b128 -> VALU-bound.
// ---------------------------------------------------------------------------
__global__ __launch_bounds__(256)
void adjk_f32(const float* __restrict__ adj, const float* __restrict__ qk,
              float* __restrict__ kapart) {
  __shared__ __align__(16) float As[KT][129];  // [kk][row], padded
  __shared__ __align__(16) float Ks[KT][68];   // [kk][col], padded (16B-mult)
  const int tid = threadIdx.x;
  const int b    = blockIdx.z;
  const int row0 = blockIdx.x * MT;
  const int k0   = blockIdx.y * KCHUNK;
  const float* A  = adj + (size_t)b * N_ * N_;
  const float* Qb = qk + (size_t)b * N_ * QKD + ATT;  // k part of qk rows

  const int tx = tid & 15;        // col group: cols 4*tx .. 4*tx+3
  const int ty = tid >> 4;        // row group: rows 8*ty .. 8*ty+7

  float acc[8][4] = {};

  for (int kt = 0; kt < KCHUNK; kt += KT) {
    // stage A-tile transposed: 128 rows x 64 k -> As[kk][row]
#pragma unroll
    for (int i = 0; i < 8; ++i) {
      const int f = tid + i * 256;       // 0..2047
      const int r = f >> 4;              // 0..127
      const int c4 = (f & 15) << 2;      // 0..60
      const float4 v = *(const float4*)(A + (size_t)(row0 + r) * N_ + k0 + kt + c4);
      As[c4 + 0][r] = v.x; As[c4 + 1][r] = v.y;
      As[c4 + 2][r] = v.z; As[c4 + 3][r] = v.w;
    }
    // stage k-tile: 64 m-rows x 64 cols (direct copy, strided source)
#pragma unroll
    for (int i = 0; i < 4; ++i) {
      const int f = tid + i * 256;       // 0..1023
      const int m = f >> 4;              // 0..63
      const int c4 = (f & 15) << 2;      // 0..60
      *(float4*)&Ks[m][c4] =
          *(const float4*)(Qb + (size_t)(k0 + kt + m) * QKD + c4);
    }
    __syncthreads();

#pragma unroll 8
    for (int kk = 0; kk < KT; ++kk) {
      const float4 a0 = *(const float4*)&As[kk][(ty << 3)];
      const float4 a1 = *(const float4*)&As[kk][(ty << 3) + 4];
      const float4 bv = *(const float4*)&Ks[kk][(tx << 2)];
      const float av[8] = {a0.x, a0.y, a0.z, a0.w, a1.x, a1.y, a1.z, a1.w};
      const float bb[4] = {bv.x, bv.y, bv.z, bv.w};
#pragma unroll
      for (int i = 0; i < 8; ++i)
#pragma unroll
        for (int j = 0; j < 4; ++j) acc[i][j] += av[i] * bb[j];
    }
    __syncthreads();
  }

  // write partials: kapart[split][b*N + row][col]
  float* outp = kapart + ((size_t)blockIdx.y * B_ * N_ + (size_t)b * N_) * ATT;
#pragma unroll
  for (int i = 0; i < 8; ++i) {
    const int row = row0 + (ty << 3) + i;
    float4 o = make_float4(acc[i][0], acc[i][1], acc[i][2], acc[i][3]);
    *(float4*)(outp + (size_t)row * ATT + (tx << 2)) = o;
  }
}

// ---------------------------------------------------------------------------
// wpre[row] = (1/8) * q[row] . (sum of KSPLIT ka partials)  — one wave/row
// ---------------------------------------------------------------------------
__global__ __launch_bounds__(256)
void qdot(const float* __restrict__ qk, const float* __restrict__ kapart,
          float* __restrict__ wpre) {
  const int wid  = threadIdx.x >> 6;
  const int lane = threadIdx.x & 63;
  const int row  = blockIdx.x * 4 + wid;   // b*N + n

  float ka = 0.f;
#pragma unroll
  for (int s = 0; s < KSPLIT; ++s)
    ka += kapart[((size_t)s * B_ * N_ + row) * ATT + lane];

  const float q = qk[(size_t)row * QKD + lane];
  float val = q * ka;
#pragma unroll
  for (int off = 32; off; off >>= 1) val += __shfl_xor(val, off);
  if (lane == 0) wpre[row] = val * 0.125f;   // 1/sqrt(64)
}

// ---------------------------------------------------------------------------
// Softmax over the bag dimension (N=4096) per batch, in-place.
// ---------------------------------------------------------------------------
__global__ __launch_bounds__(256)
void softmax_bag(float* __restrict__ w) {
  __shared__ float red[256];
  const int b = blockIdx.x;
  float* wb = w + (size_t)b * N_;
  const int t = threadIdx.x;

  float vals[16];
  float mx = -1e30f;
#pragma unroll
  for (int i = 0; i < 16; ++i) {
    vals[i] = wb[t + i * 256];
    mx = fmaxf(mx, vals[i]);
  }
  red[t] = mx; __syncthreads();
  for (int s = 128; s; s >>= 1) {
    if (t < s) red[t] = fmaxf(red[t], red[t + s]);
    __syncthreads();
  }
  mx = red[0];
  __syncthreads();

  float sum = 0.f;
#pragma unroll
  for (int i = 0; i < 16; ++i) {
    vals[i] = expf(vals[i] - mx);
    sum += vals[i];
  }
  red[t] = sum; __syncthreads();
  for (int s = 128; s; s >>= 1) {
    if (t < s) red[t] += red[t + s];
    __syncthreads();
  }
  const float inv = 1.f / red[0];
#pragma unroll
  for (int i = 0; i < 16; ++i) wb[t + i * 256] = vals[i] * inv;
}

// ---------------------------------------------------------------------------
// out[b,n,:] *= w[b,n]   (v was written directly into d_out)
// ---------------------------------------------------------------------------
__global__ __launch_bounds__(256)
void scale_v(float* __restrict__ out, const float* __restrict__ w, int total4) {
  int idx = blockIdx.x * blockDim.x + threadIdx.x;
  const int stride = gridDim.x * blockDim.x;
  for (; idx < total4; idx += stride) {
    float4 v = ((const float4*)out)[idx];
    const float s = w[idx >> 7];                  // 512/4 = 128 float4 per row
    v.x *= s; v.y *= s; v.z *= s; v.w *= s;
    ((float4*)out)[idx] = v;
  }
}

extern "C" void kernel_launch(void* const* d_in, const int* in_sizes, int n_in,
                              void* d_out, int out_size, void* d_ws, size_t ws_size,
                              hipStream_t stream) {
  const float* x    = (const float*)d_in[0];   // (B,N,512)
  const float* adj  = (const float*)d_in[1];   // (B,N,N)
  const float* W_qk = (const float*)d_in[2];   // (128,512)
  const float* W_v  = (const float*)d_in[3];   // (512,512)
  float* out = (float*)d_out;                  // (B,N,512)

  float* qk     = (float*)d_ws;                           // B*N*128 f32 (8 MB)
  float* kapart = qk + (size_t)B_ * N_ * QKD;             // KSPLIT*B*N*64 (16 MB)
  float* wpre   = kapart + (size_t)KSPLIT * B_ * N_ * ATT; // B*N f32

  const int M = B_ * N_;  // 16384

  // v = x @ W_v^T  -> directly into d_out
  {
    dim3 grid(M / 64, IND / 64);
    gemm_nt_f32<<<grid, 256, 0, stream>>>(x, W_v, out, M, IND, IND);
  }
  // qk = x @ W_qk^T -> workspace
  {
    dim3 grid(M / 64, QKD / 64);
    gemm_nt_f32<<<grid, 256, 0, stream>>>(x, W_qk, qk, M, IND, QKD);
  }
  // ka partials = adj @ k (dense f32 split-K GEMM)
  {
    dim3 grid(N_ / MT, KSPLIT, B_);
    adjk_f32<<<grid, 256, 0, stream>>>(adj, qk, kapart);
  }
  // wpre = q . ka / 8
  qdot<<<M / 4, 256, 0, stream>>>(qk, kapart, wpre);
  // softmax over bag dim
  softmax_bag<<<B_, 256, 0, stream>>>(wpre);
  // out *= w
  const int total4 = M * (IND / 4);
  scale_v<<<2048, 256, 0, stream>>>(out, wpre, total4);
}